// Round 5
// baseline (138.261 us; speedup 1.0000x reference)
//
#include <hip/hip_runtime.h>

// ---------------------------------------------------------------------------
// ConvQuantizationWrapper: exact integer reformulation, MFMA i8, fully fused.
// out = [conv3x3(q_in, tc(q_w)) + zp*conv3x3(ones, q_w)] / (sa*sw) + bias
//   q_in = clip(round(x*sa - zp), 0, 255) (u8);  q_w = round(w*sw)
//
// R9: R4 post-mortem: conflicts fixed (1.04M->237K) but conv stuck at 43.9us
// with EVERYTHING low (Mfma 5.8%, VALU 19.8%, HBM 26%, Occ 22%) and traffic
// minimal (38+53MB) => memory-latency bound from insufficient MLP: grid 896
// = 3.5 blocks/CU; waves hold <=8KB in flight only during phase 1; Little's
// law needs ~9.4KB/CU sustained for 6.4TB/s. Fix: 2-output-row blocks ->
// grid 1792 = 7.0 blocks/CU exactly, LDS 14.8KB (8 fit), launch_bounds
// (256,8) caps VGPR at 64 (safe: only Ba[9]=36 B-frag regs now; R4 fit 60
// with 72). Each wave owns one 16-och group x 7 M-tiles x 9 taps. Halo
// amplification 1.5x->2x is L3-absorbed; +33% quant VALU is cheap vs 2x
// parallelism. Kept: XOR-swizzled LDS (conflict-free ds_read_b128), scalar
// quant (m240), XCD swizzle (8 x 224), plain float4 stores.
// ---------------------------------------------------------------------------

typedef int v4i __attribute__((ext_vector_type(4)));
typedef float v4f __attribute__((ext_vector_type(4)));

// ---- fused weight prep: quantize + 9-case border-correction table ----
__global__ __launch_bounds__(64) void prep_wq(const float* __restrict__ wt,
                                              const float* __restrict__ sw_p,
                                              const float* __restrict__ zp_p,
                                              signed char* __restrict__ w8,
                                              float* __restrict__ corr_tab) {
  const int o = blockIdx.x;             // 0..63
  const int i = threadIdx.x;            // input channel 0..63
  const float sw = sw_p[0];
  const float* wp = wt + (size_t)(o * 64 + i) * 9;
  int q[9];
#pragma unroll
  for (int k = 0; k < 9; ++k) q[k] = (int)rintf(wp[k] * sw);
#pragma unroll
  for (int k = 0; k < 9; ++k)
    w8[(o * 9 + k) * 64 + i] = (signed char)(q[k] & 255);

  int stc[9], srw[9];
#pragma unroll
  for (int k = 0; k < 9; ++k) {
    int a = (int)(signed char)(q[k] & 255);   // two's-complement i8 value
    int b = q[k];
#pragma unroll
    for (int off = 32; off; off >>= 1) {      // xor butterfly: sum in ALL lanes
      a += __shfl_xor(a, off);
      b += __shfl_xor(b, off);
    }
    stc[k] = a; srw[k] = b;
  }
  const float zp = zp_p[0];
  if (i < 9) {                          // lane i computes border case i
    const int v = i / 3, hc = i % 3;
    float corr = 0.0f;
#pragma unroll
    for (int k = 0; k < 9; ++k) {
      const int kh = k / 3, kw = k % 3;
      const bool drop = (v == 1 && kh == 0) || (v == 2 && kh == 2) ||
                        (hc == 1 && kw == 0) || (hc == 2 && kw == 2);
      if (!drop) corr += 128.0f * (float)stc[k] + zp * (float)srw[k];
    }
    corr_tab[i * 64 + o] = corr;
  }
}

// ---- fused quantize + conv: LDS-staged implicit GEMM on mfma_i32_16x16x64 ----
// grid 1792 (1D, XCD-swizzled): block = one n, 2 output rows (112 px), 64 och.
// qa LDS layout: group g = row*58 + col (64B = 4 16B units); channel-unit u
// lives at unit u ^ ((col>>1)&3)  -> ds_read_b128 A-frags conflict-free.
// Phase 1: 1024 tasks (= 4*256). idx -> cg = idx&15 (channel dword),
// rem = idx>>4 (0..63): row = rem/14 (qa row 0..3), w4 = rem%14 (pixel quad).
// Phase 2: 4 waves, wave = one 16-och group; 7 M-tiles of 16 px; per tile
// 9 ds_read_b128 A-frags, each feeding 1 MFMA.
__global__ __launch_bounds__(256, 8) void conv_fused(
    const float* __restrict__ x, const signed char* __restrict__ w8,
    const float* __restrict__ corr_tab, const float* __restrict__ bias,
    const float* __restrict__ sa_p, const float* __restrict__ sw_p,
    const float* __restrict__ zp_p, float* __restrict__ out) {
  __shared__ __align__(16) signed char lds[14848];   // 4*58 groups * 64B
  const int tid = threadIdx.x;
  // XCD swizzle: 1792 = 8 xcd * 224; contiguous 224 work-items (8 images of
  // 28 slices) per XCD so halo-sharing neighbor blocks hit the same L2.
  const int b = blockIdx.x;
  const int g = (b & 7) * 224 + (b >> 3);
  const int n = (g * 2341) >> 16;       // g / 28 (exact for g < 1792)
  const int h0 = (g - n * 28) * 2;      // output rows h0, h0+1
  const float sa = sa_p[0], zp = zp_p[0];
  const float* xim = x + (size_t)n * 200704;    // 64 * 3136

  // ---- phase 1: quantize 4 padded rows directly into LDS ----
#pragma unroll 2
  for (int it = 0; it < 4; ++it) {
    const int idx = tid + 256 * it;     // 0..1023
    if (idx < 896) {                    // quant tasks
      const int cg = idx & 15;
      const int rem = idx >> 4;         // 0..55
      const int row = (rem * 2341) >> 15;   // rem / 14 (exact)
      const int w4 = rem - row * 14;
      const int ih = h0 - 1 + row;
      const bool valid = (unsigned)ih < 56u;
      v4f v[4];
      if (valid) {
#pragma unroll
        for (int j = 0; j < 4; ++j)
          v[j] = *(const v4f*)(xim + (size_t)(cg * 4 + j) * 3136 + ih * 56 + w4 * 4);
      }
#pragma unroll
      for (int e = 0; e < 4; ++e) {
        int dw = 0;
        if (valid) {
#pragma unroll
          for (int j = 0; j < 4; ++j) {
            float tq;
            {
#pragma clang fp contract(off)
              tq = v[j][e] * sa - zp;   // match ref: mul then sub, no fma
            }
            float qf = rintf(tq);       // half-to-even, like jnp.round
            qf = fminf(fmaxf(qf, 0.0f), 255.0f);
            const int bb = ((int)qf - 128) & 255;
            dw |= bb << (8 * j);
          }
        }
        const int c = w4 * 4 + 1 + e;   // stored column
        const int t = (c >> 1) & 3;     // unit swizzle
        ((int*)lds)[(row * 58 + c) * 16 + (((cg >> 2) ^ t) << 2) + (cg & 3)] = dw;
      }
    } else {                            // col pads: col 0 and col 57, 4 rows
      const int z = idx - 896;          // 0..127
      const int loc = z >> 4, d = z & 15;
      const int row = loc >> 1, side = loc & 1;
      ((int*)lds)[(row * 58 + side * 57) * 16 + d] = 0;
    }
  }
  __syncthreads();

  // ---- phase 2: MFMA implicit GEMM; wave = one 16-och group ----
  const int lane = tid & 63;
  const int wv = tid >> 6;              // och group
  const int ln = lane & 15;
  const int kg = lane >> 4;             // k-group: bytes kg*16..kg*16+15
  const int oa = wv * 16 + ln;          // this wave's och

  // B fragments: B[n=ln][k = kg*16 + j] per tap
  const signed char* wba = w8 + (size_t)oa * 576 + kg * 16;
  v4i Ba[9];
#pragma unroll
  for (int t = 0; t < 9; ++t) Ba[t] = *(const v4i*)(wba + t * 64);

  const float sw = sw_p[0];
  const float rden = 1.0f / (sw * sa);
  const float boa = bias[oa];
  const float cFa = corr_tab[oa];       // interior (case 0) correction (L2)
  float* const outa = out + (size_t)(n * 64 + oa) * 3136 + h0 * 56;

#pragma unroll 1
  for (int t = 0; t < 7; ++t) {
    const int pb = t * 16;              // block-relative px tile base (0..96)
    const int pa = pb + ln;             // this lane's A-row px (0..111)
    const int hr = pa >= 56;            // qa base row - 0 or 1 (+1 per kh)
    const int wc = pa - hr * 56;
    // per-kw column byte offsets incl. unit swizzle (c = wc+kw, 0..57)
    int coff[3];
#pragma unroll
    for (int kw = 0; kw < 3; ++kw) {
      const int c = wc + kw;
      coff[kw] = c * 64 + ((kg ^ ((c >> 1) & 3)) << 4);
    }
    const signed char* rowb = lds + hr * 3712;    // 58*64 per qa row
    v4i acca = {0, 0, 0, 0};
#pragma unroll
    for (int kh = 0; kh < 3; ++kh) {
#pragma unroll
      for (int kw = 0; kw < 3; ++kw) {
        const v4i A = *(const v4i*)(rowb + kh * 3712 + coff[kw]);
        acca = __builtin_amdgcn_mfma_i32_16x16x64_i8(A, Ba[kh * 3 + kw], acca, 0, 0, 0);
      }
    }
    // epilogue: C/D row(px) = kg*4 + reg, col(och) = ln
    const int pxb = pb + kg * 4;
    float ta[4];
#pragma unroll
    for (int e = 0; e < 4; ++e) {
      const int px = pxb + e;
      const int hh = px >= 56;
      const int ww = px - hh * 56;
      const int hg = h0 + hh;
      float ca = cFa;
      if ((hg == 0) | (hg == 55) | (ww == 0) | (ww == 55)) {   // rare border
        const int vcase = (hg == 0) ? 1 : ((hg == 55) ? 2 : 0);
        const int hcase = (ww == 0) ? 1 : ((ww == 55) ? 2 : 0);
        ca = corr_tab[(vcase * 3 + hcase) * 64 + oa];
      }
      ta[e] = ((float)acca[e] + ca) * rden + boa;
    }
    *(float4*)(outa + pxb) = make_float4(ta[0], ta[1], ta[2], ta[3]);
  }
}

extern "C" void kernel_launch(void* const* d_in, const int* in_sizes, int n_in,
                              void* d_out, int out_size, void* d_ws, size_t ws_size,
                              hipStream_t stream) {
  const float* x    = (const float*)d_in[0];
  const float* wt   = (const float*)d_in[1];
  const float* bias = (const float*)d_in[2];
  const float* sa   = (const float*)d_in[3];
  const float* sw   = (const float*)d_in[4];
  const float* zp   = (const float*)d_in[5];
  float* out = (float*)d_out;

  char* ws = (char*)d_ws;
  signed char* w8 = (signed char*)ws;                 // 36,864 B
  float* corr_tab = (float*)(ws + 36864);             // 2,304 B

  prep_wq<<<64, 64, 0, stream>>>(wt, sw, zp, w8, corr_tab);
  conv_fused<<<1792, 256, 0, stream>>>(x, w8, corr_tab, bias, sa, sw, zp, out);
}

// Round 6
// 128.258 us; speedup vs baseline: 1.0780x; 1.0780x over previous
//
#include <hip/hip_runtime.h>

// ---------------------------------------------------------------------------
// ConvQuantizationWrapper: exact integer reformulation, MFMA i8, TWO-PASS.
// out = [conv3x3(q_in, tc(q_w)) + zp*conv3x3(ones, q_w)] / (sa*sw) + bias
//   q_in = clip(round(x*sa - zp), 0, 255) (u8);  q_w = round(w*sw)
//
// R10: DE-FUSE. Evidence: R0's two-pass moved ~136MB at ~3.4TB/s/pass
// (~40us); every fused variant (R3/R4/R5) moved ~90MB at only ~2.0TB/s
// (44-50us) with ALL pipes <25% at 22% AND 43% occupancy. Mechanism: fused
// blocks run in lockstep -> each CU alternates all-memory phase 1 (86KB +
// quant VALU) and memory-idle MFMA phase 2 across a barrier; pipes sum
// instead of overlapping. Two-pass restores overlap: quant is pure streaming
// (no barrier/MFMA), conv's staging is 4x cheaper (22KB compact i8). The qa
// round-trip (13.8MB) is L2/L3-resident.
// Kept from R4 (proven): scalar quant math (m240: asm cvt_pk -37%), XOR
// bank-swizzle (conflicts 1.04M->237K), XCD swizzle, (256,4) VGPR regime,
// 4-row blocks (aligned 896B och-rows, no write amplification).
// New: swizzle pre-baked into GLOBAL qa layout (m173) so quant writes it
// directly (no LDS in quant at all) and conv stages linearly.
// ---------------------------------------------------------------------------

typedef int v4i __attribute__((ext_vector_type(4)));
typedef float v4f __attribute__((ext_vector_type(4)));

#define QA_ROW 3712          // 58 cols * 64 B
#define QA_IMG 215296        // 58 rows * QA_ROW

// ---- fused weight prep: quantize + 9-case border-correction table ----
__global__ __launch_bounds__(64) void prep_wq(const float* __restrict__ wt,
                                              const float* __restrict__ sw_p,
                                              const float* __restrict__ zp_p,
                                              signed char* __restrict__ w8,
                                              float* __restrict__ corr_tab) {
  const int o = blockIdx.x;             // 0..63
  const int i = threadIdx.x;            // input channel 0..63
  const float sw = sw_p[0];
  const float* wp = wt + (size_t)(o * 64 + i) * 9;
  int q[9];
#pragma unroll
  for (int k = 0; k < 9; ++k) q[k] = (int)rintf(wp[k] * sw);
#pragma unroll
  for (int k = 0; k < 9; ++k)
    w8[(o * 9 + k) * 64 + i] = (signed char)(q[k] & 255);

  int stc[9], srw[9];
#pragma unroll
  for (int k = 0; k < 9; ++k) {
    int a = (int)(signed char)(q[k] & 255);   // two's-complement i8 value
    int b = q[k];
#pragma unroll
    for (int off = 32; off; off >>= 1) {      // xor butterfly: sum in ALL lanes
      a += __shfl_xor(a, off);
      b += __shfl_xor(b, off);
    }
    stc[k] = a; srw[k] = b;
  }
  const float zp = zp_p[0];
  if (i < 9) {                          // lane i computes border case i
    const int v = i / 3, hc = i % 3;
    float corr = 0.0f;
#pragma unroll
    for (int k = 0; k < 9; ++k) {
      const int kh = k / 3, kw = k % 3;
      const bool drop = (v == 1 && kh == 0) || (v == 2 && kh == 2) ||
                        (hc == 1 && kw == 0) || (hc == 2 && kw == 2);
      if (!drop) corr += 128.0f * (float)stc[k] + zp * (float)srw[k];
    }
    corr_tab[i * 64 + o] = corr;
  }
}

// ---- quantize: NCHW fp32 -> padded, PRE-SWIZZLED "NHWC" i8 (q_in - 128) ----
// Pure streaming, no LDS, no barrier. grid (14, 64): block = 4 input rows.
// qa layout: (n, qrow=ih+1, col=w+1) is a 64B group of 4 16B units; channel
// unit u is stored at u ^ ((col>>1)&3). Per 16-lane group (cg 0..15, same
// pixel) the 16 dword stores cover the 64B group exactly -> 4 full lines per
// wave-store. Loads: lane pattern cg-fastest -> 16 full 64B lines per
// wave-load (the 1KB minimum).
__global__ __launch_bounds__(256) void quant_a(const float* __restrict__ x,
                                               const float* __restrict__ sa_p,
                                               const float* __restrict__ zp_p,
                                               signed char* __restrict__ qa) {
  const int bx = blockIdx.x;            // 0..13 -> input rows 4bx..4bx+3
  const int n = blockIdx.y;
  const int tid = threadIdx.x;
  const float sa = sa_p[0], zp = zp_p[0];
  const float* xim = x + (size_t)n * 200704;      // 64 * 3136
  signed char* const qim = qa + (size_t)n * QA_IMG;

#pragma unroll
  for (int it = 0; it < 4; ++it) {
    const int idx = tid + 256 * it;     // 0..1023
    if (idx < 896) {                    // quant tasks
      const int cg = idx & 15;          // channel dword (ch 4cg..4cg+3)
      const int rem = idx >> 4;         // 0..55
      const int r = (rem * 2341) >> 15; // rem / 14 (exact)
      const int w4 = rem - r * 14;      // pixel quad
      const int ih = bx * 4 + r;        // 0..55, always valid
      v4f v[4];
#pragma unroll
      for (int j = 0; j < 4; ++j)
        v[j] = *(const v4f*)(xim + (size_t)(cg * 4 + j) * 3136 + ih * 56 + w4 * 4);
#pragma unroll
      for (int e = 0; e < 4; ++e) {
        int dw = 0;
#pragma unroll
        for (int j = 0; j < 4; ++j) {
          float tq;
          {
#pragma clang fp contract(off)
            tq = v[j][e] * sa - zp;     // match ref: mul then sub, no fma
          }
          float qf = rintf(tq);         // half-to-even, like jnp.round
          qf = fminf(fmaxf(qf, 0.0f), 255.0f);
          dw |= (((int)qf - 128) & 255) << (8 * j);
        }
        const int c = w4 * 4 + 1 + e;   // stored column 1..56
        const int t = (c >> 1) & 3;     // baked unit swizzle
        *(int*)(qim + (ih + 1) * QA_ROW + c * 64 +
                (((cg >> 2) ^ t) << 4) + ((cg & 3) << 2)) = dw;
      }
    } else {                            // col pads: col 0 and 57, 4 qa rows
      const int z = idx - 896;          // 0..127
      const int loc = z >> 4, d = z & 15;
      const int r = loc >> 1, side = loc & 1;
      *(int*)(qim + (bx * 4 + 1 + r) * QA_ROW + side * 57 * 64 + d * 4) = 0;
    }
  }
  if (bx == 0 && tid < 232)             // top pad row (swizzle-invariant zeros)
    ((uint4*)qim)[tid] = make_uint4(0, 0, 0, 0);
  if (bx == 13 && tid < 232)            // bottom pad row
    ((uint4*)(qim + (size_t)57 * QA_ROW))[tid] = make_uint4(0, 0, 0, 0);
}

// ---- conv: LDS-staged implicit GEMM on v_mfma_i32_16x16x64_i8 ----
// grid 896 (1D, XCD-swizzled): block = one n, 4 output rows (224 px), 64 och.
// Staging is LINEAR (global qa is pre-swizzled): 1392 uint4. Phase 2: 4
// waves = (px-half) x (och-pair); 7 M-tiles of 16 px; per tile 9 swizzled
// conflict-free ds_read_b128 A-frags, each feeding 2 MFMAs (och oa, oa+16).
__global__ __launch_bounds__(256, 4) void conv_mfma(
    const signed char* __restrict__ qa, const signed char* __restrict__ w8,
    const float* __restrict__ corr_tab, const float* __restrict__ bias,
    const float* __restrict__ sa_p, const float* __restrict__ sw_p,
    float* __restrict__ out) {
  __shared__ __align__(16) signed char lds[22272];   // 6*58 groups * 64B
  const int tid = threadIdx.x;
  // XCD swizzle: 896 = 8 xcd * 112 -> each XCD owns 8 whole images; blocks
  // sharing halo rows co-locate on one L2.
  const int b = blockIdx.x;
  const int g = (b & 7) * 112 + (b >> 3);
  const int n = (g * 2341) >> 15;       // g / 14 (exact for g < 896)
  const int h0 = (g - n * 14) * 4;      // output rows h0..h0+3

  // stage qa rows h0..h0+5 (input rows h0-1..h0+4), 1392 uint4, linear
  {
    const uint4* src = (const uint4*)(qa + (size_t)n * QA_IMG + (size_t)h0 * QA_ROW);
    uint4* dst = (uint4*)lds;
#pragma unroll
    for (int it = 0; it < 6; ++it) {
      const int idx = tid + it * 256;
      if (idx < 1392) dst[idx] = src[idx];
    }
  }
  __syncthreads();

  const int lane = tid & 63;
  const int wv = tid >> 6;
  const int phalf = wv & 1;             // px offset 112*phalf
  const int ogp = wv >> 1;              // och 32*ogp
  const int ln = lane & 15;
  const int kg = lane >> 4;             // k-group: bytes kg*16..kg*16+15
  const int oa = ogp * 32 + ln;         // first och; second is oa+16

  // B fragments for both och groups: B[n=ln][k = kg*16 + j] per tap
  const signed char* wba = w8 + (size_t)oa * 576 + kg * 16;
  v4i Ba[9], Bb[9];
#pragma unroll
  for (int t = 0; t < 9; ++t) {
    Ba[t] = *(const v4i*)(wba + t * 64);
    Bb[t] = *(const v4i*)(wba + 9216 + t * 64);   // (oa+16)*576
  }

  const float sa = sa_p[0], sw = sw_p[0];
  const float rden = 1.0f / (sw * sa);
  const float boa = bias[oa], bob = bias[oa + 16];
  const float cFa = corr_tab[oa];       // interior (case 0) corrections (L2)
  const float cFb = corr_tab[oa + 16];
  float* const outa = out + (size_t)(n * 64 + oa) * 3136 + h0 * 56;
  float* const outb = outa + 16 * 3136;

#pragma unroll 1
  for (int t = 0; t < 7; ++t) {
    const int pb = phalf * 112 + t * 16;          // block-relative px tile base
    const int pa = pb + ln;                       // this lane's A-row px (0..223)
    const int hr = (pa * 9363) >> 19;             // pa / 56 (exact)
    const int wc = pa - hr * 56;
    // per-kw column byte offsets incl. unit swizzle (c = wc+kw, 0..57)
    int coff[3];
#pragma unroll
    for (int kw = 0; kw < 3; ++kw) {
      const int c = wc + kw;
      coff[kw] = c * 64 + ((kg ^ ((c >> 1) & 3)) << 4);
    }
    const signed char* rowb = lds + hr * QA_ROW;
    v4i acca = {0, 0, 0, 0}, accb = {0, 0, 0, 0};
#pragma unroll
    for (int kh = 0; kh < 3; ++kh) {
#pragma unroll
      for (int kw = 0; kw < 3; ++kw) {
        const v4i A = *(const v4i*)(rowb + kh * QA_ROW + coff[kw]);
        acca = __builtin_amdgcn_mfma_i32_16x16x64_i8(A, Ba[kh * 3 + kw], acca, 0, 0, 0);
        accb = __builtin_amdgcn_mfma_i32_16x16x64_i8(A, Bb[kh * 3 + kw], accb, 0, 0, 0);
      }
    }
    // epilogue: C/D row(px) = kg*4 + reg, col(och) = ln
    const int pxb = pb + kg * 4;
    float ta[4], tb[4];
#pragma unroll
    for (int e = 0; e < 4; ++e) {
      const int px = pxb + e;
      const int hh = (px * 9363) >> 19;
      const int ww = px - hh * 56;
      const int hg = h0 + hh;
      float ca = cFa, cb = cFb;
      if ((hg == 0) | (hg == 55) | (ww == 0) | (ww == 55)) {   // rare border
        const int vcase = (hg == 0) ? 1 : ((hg == 55) ? 2 : 0);
        const int hcase = (ww == 0) ? 1 : ((ww == 55) ? 2 : 0);
        const int cidx = (vcase * 3 + hcase) * 64;
        ca = corr_tab[cidx + oa];
        cb = corr_tab[cidx + oa + 16];
      }
      ta[e] = ((float)acca[e] + ca) * rden + boa;
      tb[e] = ((float)accb[e] + cb) * rden + bob;
    }
    *(float4*)(outa + pxb) = make_float4(ta[0], ta[1], ta[2], ta[3]);
    *(float4*)(outb + pxb) = make_float4(tb[0], tb[1], tb[2], tb[3]);
  }
}

extern "C" void kernel_launch(void* const* d_in, const int* in_sizes, int n_in,
                              void* d_out, int out_size, void* d_ws, size_t ws_size,
                              hipStream_t stream) {
  const float* x    = (const float*)d_in[0];
  const float* wt   = (const float*)d_in[1];
  const float* bias = (const float*)d_in[2];
  const float* sa   = (const float*)d_in[3];
  const float* sw   = (const float*)d_in[4];
  const float* zp   = (const float*)d_in[5];
  float* out = (float*)d_out;

  char* ws = (char*)d_ws;
  signed char* qa = (signed char*)ws;                       // 13,778,944 B
  signed char* w8 = (signed char*)(ws + 13778944);          // 36,864 B
  float* corr_tab = (float*)(ws + 13778944 + 36864);        // 2,304 B

  prep_wq<<<64, 64, 0, stream>>>(wt, sw, zp, w8, corr_tab);
  quant_a<<<dim3(14, 64), 256, 0, stream>>>(x, sa, zp, qa);
  conv_mfma<<<896, 256, 0, stream>>>(qa, w8, corr_tab, bias, sa, sw, out);
}

// Round 8
// 125.098 us; speedup vs baseline: 1.1052x; 1.0253x over previous
//
#include <hip/hip_runtime.h>

// ---------------------------------------------------------------------------
// ConvQuantizationWrapper: exact integer reformulation, MFMA i8, fully fused.
// out = [conv3x3(q_in, tc(q_w)) + zp*conv3x3(ones, q_w)] / (sa*sw) + bias
//   q_in = clip(round(x*sa - zp), 0, 255) (u8);  q_w = round(w*sw)
//
// R12: RESTORE R2 (session-best, 125.7us measured). R7's cooperative-kernel
// attempt never launched (hipLaunchCooperativeKernel fails in this harness;
// timed path is hipGraph-captured and coop launches aren't capturable ->
// out stayed memset-zero, absmax 132). Session A/B map (controllable slice
// = total - ~86.4us fixed harness fills): R2 plain fused 39.3 / R0 plain
// 2-pass 39.6 / R6 swizzled 2-pass 41.9 / R4 swizzled fused 45.0 / R3
// asm-quant 50.2 / R5 high-occ 51.9. Every deviation from this kernel
// regressed or failed: bank-XOR-swizzle (+2.6us: conflicts weren't
// critical-path), XCD swizzle (bundled, net-negative), inline-asm cvt_pk
// (m240 confirmed, -37%), occupancy 2x via (256,8) (slower: VGPR 32 gutted
// ILP), pre-swizzled global qa (+2.6us), cooperative fusion (no launch).
// Structure: one kernel, per-block {quantize 6 input rows -> LDS qa tile
// (direct packed-dword, 1 barrier) -> 4-wave MFMA implicit GEMM}; ROWB=80
// pad; scalar quant math; plain float4 stores; plain blockIdx mapping.
// ---------------------------------------------------------------------------

typedef int v4i __attribute__((ext_vector_type(4)));

#define ROWB 80   // LDS bytes per qa (row,col) entry: 64 data + 16 pad

// ---- fused weight prep: quantize + 9-case border-correction table ----
__global__ __launch_bounds__(64) void prep_wq(const float* __restrict__ wt,
                                              const float* __restrict__ sw_p,
                                              const float* __restrict__ zp_p,
                                              signed char* __restrict__ w8,
                                              float* __restrict__ corr_tab) {
  const int o = blockIdx.x;             // 0..63
  const int i = threadIdx.x;            // input channel 0..63
  const float sw = sw_p[0];
  const float* wp = wt + (size_t)(o * 64 + i) * 9;
  int q[9];
#pragma unroll
  for (int k = 0; k < 9; ++k) q[k] = (int)rintf(wp[k] * sw);
#pragma unroll
  for (int k = 0; k < 9; ++k)
    w8[(o * 9 + k) * 64 + i] = (signed char)(q[k] & 255);

  int stc[9], srw[9];
#pragma unroll
  for (int k = 0; k < 9; ++k) {
    int a = (int)(signed char)(q[k] & 255);   // two's-complement i8 value
    int b = q[k];
#pragma unroll
    for (int off = 32; off; off >>= 1) {      // xor butterfly: sum in ALL lanes
      a += __shfl_xor(a, off);
      b += __shfl_xor(b, off);
    }
    stc[k] = a; srw[k] = b;
  }
  const float zp = zp_p[0];
  if (i < 9) {                          // lane i computes border case i
    const int v = i / 3, hc = i % 3;
    float corr = 0.0f;
#pragma unroll
    for (int k = 0; k < 9; ++k) {
      const int kh = k / 3, kw = k % 3;
      const bool drop = (v == 1 && kh == 0) || (v == 2 && kh == 2) ||
                        (hc == 1 && kw == 0) || (hc == 2 && kw == 2);
      if (!drop) corr += 128.0f * (float)stc[k] + zp * (float)srw[k];
    }
    corr_tab[i * 64 + o] = corr;
  }
}

// ---- fused quantize + conv: LDS-staged implicit GEMM on mfma_i32_16x16x64 ----
// grid (14, 64): block = one n, 4 output rows (224 px), all 64 och.
// Phase 1: 1536 tasks (= 6*256). idx -> cg = idx&15 (channel group of 4),
// rem = idx>>4, row = rem/14 (qa row 0..5), w4 = rem%14 (pixel quad).
// Phase 2: 4 waves = (px-half) x (och-pair); 7 M-tiles of 16 px each; per
// tile 9 ds_read_b128 A-frags, each feeding 2 MFMAs (och oa, oa+16).
__global__ __launch_bounds__(256, 4) void conv_fused(
    const float* __restrict__ x, const signed char* __restrict__ w8,
    const float* __restrict__ corr_tab, const float* __restrict__ bias,
    const float* __restrict__ sa_p, const float* __restrict__ sw_p,
    const float* __restrict__ zp_p, float* __restrict__ out) {
  __shared__ __align__(16) signed char lds[6 * 58 * ROWB];   // 27,840 B
  const int tid = threadIdx.x;
  const int n = blockIdx.y;
  const int h0 = blockIdx.x * 4;        // output rows h0..h0+3; qa rows h0-1..h0+4
  const float sa = sa_p[0], zp = zp_p[0];
  const float* xim = x + (size_t)n * 200704;    // 64 * 3136

  // ---- phase 1: quantize 6 padded rows directly into LDS ----
#pragma unroll 2
  for (int it = 0; it < 6; ++it) {
    const int idx = tid + 256 * it;     // 0..1535
    if (idx < 1344) {                   // quant tasks
      const int cg = idx & 15;
      const int rem = idx >> 4;         // 0..83
      const int row = (rem * 2341) >> 15;   // rem / 14 (exact, rem < 896)
      const int w4 = rem - row * 14;
      const int ih = h0 - 1 + row;
      const bool valid = (unsigned)ih < 56u;
      int* const dst = (int*)lds + (row * 58 + w4 * 4 + 1) * (ROWB / 4) + cg;
      if (valid) {
        float4 v[4];
#pragma unroll
        for (int j = 0; j < 4; ++j)
          v[j] = *(const float4*)(xim + (size_t)(cg * 4 + j) * 3136 + ih * 56 + w4 * 4);
#pragma unroll
        for (int e = 0; e < 4; ++e) {
          int dw = 0;
#pragma unroll
          for (int j = 0; j < 4; ++j) {
            const float xv = (&v[j].x)[e];
            float tq;
            {
#pragma clang fp contract(off)
              tq = xv * sa - zp;        // match ref: mul then sub, no fma
            }
            float qf = rintf(tq);       // half-to-even, like jnp.round
            qf = fminf(fmaxf(qf, 0.0f), 255.0f);
            const int b = ((int)qf - 128) & 255;
            dw |= b << (8 * j);
          }
          dst[e * (ROWB / 4)] = dw;
        }
      } else {
#pragma unroll
        for (int e = 0; e < 4; ++e) dst[e * (ROWB / 4)] = 0;
      }
    } else {                            // col pads: col 0 and col 57, 6 rows
      const int z = idx - 1344;         // 0..191
      const int loc = z >> 4, d = z & 15;
      const int row = loc >> 1, side = loc & 1;
      ((int*)lds)[(row * 58 + side * 57) * (ROWB / 4) + d] = 0;
    }
  }
  __syncthreads();

  // ---- phase 2: MFMA implicit GEMM ----
  const int lane = tid & 63;
  const int wv = tid >> 6;
  const int phalf = wv & 1;             // px offset 112*phalf
  const int ogp = wv >> 1;              // och 32*ogp
  const int ln = lane & 15;
  const int kg = lane >> 4;             // k-group: bytes kg*16..kg*16+15
  const int oa = ogp * 32 + ln;         // first och; second is oa+16

  // B fragments for both och groups: B[n=ln][k = kg*16 + j] per tap
  const signed char* wba = w8 + (size_t)oa * 576 + kg * 16;
  v4i Ba[9], Bb[9];
#pragma unroll
  for (int t = 0; t < 9; ++t) {
    Ba[t] = *(const v4i*)(wba + t * 64);
    Bb[t] = *(const v4i*)(wba + 9216 + t * 64);   // (oa+16)*576
  }

  const float sw = sw_p[0];
  const float rden = 1.0f / (sw * sa);
  const float boa = bias[oa], bob = bias[oa + 16];
  const float cFa = corr_tab[oa];       // interior (case 0) corrections (L2)
  const float cFb = corr_tab[oa + 16];
  float* const outa = out + (size_t)(n * 64 + oa) * 3136 + h0 * 56;
  float* const outb = outa + 16 * 3136;

#pragma unroll 1
  for (int t = 0; t < 7; ++t) {
    const int pb = phalf * 112 + t * 16;          // block-relative px tile base
    const int pa = pb + ln;                       // this lane's A-row px (0..223)
    const int hr = (pa * 9363) >> 19;             // pa / 56 (exact)
    const int wc = pa - hr * 56;
    const signed char* ab = lds + (hr * 58 + wc) * ROWB + kg * 16;
    v4i acca = {0, 0, 0, 0}, accb = {0, 0, 0, 0};
#pragma unroll
    for (int kh = 0; kh < 3; ++kh) {
#pragma unroll
      for (int kw = 0; kw < 3; ++kw) {
        const v4i A = *(const v4i*)(ab + (kh * 58 + kw) * ROWB);
        acca = __builtin_amdgcn_mfma_i32_16x16x64_i8(A, Ba[kh * 3 + kw], acca, 0, 0, 0);
        accb = __builtin_amdgcn_mfma_i32_16x16x64_i8(A, Bb[kh * 3 + kw], accb, 0, 0, 0);
      }
    }
    // epilogue: C/D row(px) = kg*4 + reg, col(och) = ln
    const int pxb = pb + kg * 4;
    float ta[4], tb[4];
#pragma unroll
    for (int e = 0; e < 4; ++e) {
      const int px = pxb + e;
      const int hh = (px * 9363) >> 19;
      const int ww = px - hh * 56;
      const int hg = h0 + hh;
      float ca = cFa, cb = cFb;
      if ((hg == 0) | (hg == 55) | (ww == 0) | (ww == 55)) {   // rare border
        const int vcase = (hg == 0) ? 1 : ((hg == 55) ? 2 : 0);
        const int hcase = (ww == 0) ? 1 : ((ww == 55) ? 2 : 0);
        const int cidx = (vcase * 3 + hcase) * 64;
        ca = corr_tab[cidx + oa];
        cb = corr_tab[cidx + oa + 16];
      }
      ta[e] = ((float)acca[e] + ca) * rden + boa;
      tb[e] = ((float)accb[e] + cb) * rden + bob;
    }
    *(float4*)(outa + pxb) = make_float4(ta[0], ta[1], ta[2], ta[3]);
    *(float4*)(outb + pxb) = make_float4(tb[0], tb[1], tb[2], tb[3]);
  }
}

extern "C" void kernel_launch(void* const* d_in, const int* in_sizes, int n_in,
                              void* d_out, int out_size, void* d_ws, size_t ws_size,
                              hipStream_t stream) {
  const float* x    = (const float*)d_in[0];
  const float* wt   = (const float*)d_in[1];
  const float* bias = (const float*)d_in[2];
  const float* sa   = (const float*)d_in[3];
  const float* sw   = (const float*)d_in[4];
  const float* zp   = (const float*)d_in[5];
  float* out = (float*)d_out;

  char* ws = (char*)d_ws;
  signed char* w8 = (signed char*)ws;                 // 36,864 B
  float* corr_tab = (float*)(ws + 36864);             // 2,304 B

  prep_wq<<<64, 64, 0, stream>>>(wt, sw, zp, w8, corr_tab);
  conv_fused<<<dim3(14, 64), 256, 0, stream>>>(x, w8, corr_tab, bias, sa, sw, zp, out);
}